// Round 7
// baseline (777.285 us; speedup 1.0000x reference)
//
#include <hip/hip_runtime.h>
#include <math.h>

#define F 256

// fused bucket-sort+gather geometry
#define SBKT_SHIFT 5
#define SBKT_ROWS 32
#define SBKT_CAP 2048     // LDS chunk capacity (16 KB); >CAP handled by chunking
#define NB_MAX 4096
#define BIN_CHUNK 16384

typedef __attribute__((ext_vector_type(8))) short short8;
typedef __attribute__((ext_vector_type(4))) float f32x4;
typedef __attribute__((ext_vector_type(2))) int i32x2;
typedef __attribute__((ext_vector_type(4))) unsigned short u16x4;
typedef __attribute__((ext_vector_type(8))) unsigned short u16x8;

__device__ __forceinline__ unsigned short f2bf(float f) {
  union { float f; unsigned u; } v; v.f = f;
  unsigned r = (v.u + 0x7fffu + ((v.u >> 16) & 1u)) >> 16;
  return (unsigned short)r;
}
__device__ __forceinline__ float bf2f(unsigned short h) {
  union { unsigned u; float f; } v; v.u = ((unsigned)h) << 16;
  return v.f;
}

// ---- prep: blocks [0,256): W[k][n] -> Wt[n][k] bf16.
//            blocks [256,256+nxb): x fp32 -> xb bf16.
//            blocks [256+nxb,..): bucket histogram of rows (block-aggregated).
__global__ void prep(const float* __restrict__ W, unsigned short* __restrict__ Wt,
                     const float* __restrict__ x, unsigned short* __restrict__ xb,
                     int NF, const int* __restrict__ rows,
                     int* __restrict__ bucket_counts, int nxb, int E, int NB) {
  if (blockIdx.x < 256) {
    int idx = blockIdx.x * 256 + threadIdx.x;
    int k = idx >> 8, n = idx & 255;
    Wt[n * F + k] = f2bf(W[k * F + n]);
    return;
  }
  int xbid = blockIdx.x - 256;
  if (xbid < nxb) {
    int i0 = xbid * 2048 + threadIdx.x * 8;
    if (i0 + 8 <= NF) {
      f32x4 a = __builtin_nontemporal_load((const f32x4*)(x + i0));
      f32x4 b = __builtin_nontemporal_load((const f32x4*)(x + i0 + 4));
      u16x8 o;
      o[0] = f2bf(a.x); o[1] = f2bf(a.y); o[2] = f2bf(a.z); o[3] = f2bf(a.w);
      o[4] = f2bf(b.x); o[5] = f2bf(b.y); o[6] = f2bf(b.z); o[7] = f2bf(b.w);
      *(u16x8*)(xb + i0) = o;
    } else {
      for (int i = i0; i < NF; ++i) xb[i] = f2bf(x[i]);
    }
    return;
  }
  // ---- bin_count part (only launched on the sort path) ----
  __shared__ unsigned hist[NB_MAX];
  const int tid = threadIdx.x;
  const int e0 = (xbid - nxb) * BIN_CHUNK;
  for (int b = tid; b < NB; b += 256) hist[b] = 0;
  __syncthreads();
  for (int k = 0; k < BIN_CHUNK / 256; ++k) {
    int e = e0 + k * 256 + tid;
    if (e < E) {
      unsigned b = (unsigned)__builtin_nontemporal_load(&rows[e]) >> SBKT_SHIFT;
      atomicAdd(&hist[b], 1u);
    }
  }
  __syncthreads();
  for (int b = tid; b < NB; b += 256)
    if (hist[b]) atomicAdd(&bucket_counts[b], (int)hist[b]);
}

// ---- exclusive scan of bucket counts (NB <= NB_MAX), one block.
// Produces bbase (segment starts, +sentinel E) and bcur (reservation cursors).
__global__ __launch_bounds__(1024) void scan_buckets(
    const int* __restrict__ bucket_counts, int* __restrict__ bbase,
    int* __restrict__ bcur, int NB, int E) {
  __shared__ int tmp[1024];
  int t = threadIdx.x;
  int carry = 0;
  for (int c0 = 0; c0 < NB; c0 += 1024) {
    int idx = c0 + t;
    int v = (idx < NB) ? bucket_counts[idx] : 0;
    tmp[t] = v;
    __syncthreads();
#pragma unroll
    for (int off = 1; off < 1024; off <<= 1) {
      int a = (t >= off) ? tmp[t - off] : 0;
      __syncthreads();
      tmp[t] += a;
      __syncthreads();
    }
    if (idx < NB) {
      int ex = carry + tmp[t] - v;
      bbase[idx] = ex;
      bcur[idx] = ex;
    }
    carry += tmp[1023];
    __syncthreads();
  }
  if (t == 0) bbase[NB] = E;
}

// ---- binning scatter into exact per-bucket segments of the edges array.
// Packs (col | row_local<<20, val). Dense per-block runs -> mostly-full lines.
__global__ __launch_bounds__(512) void bin_edges(
    const int* __restrict__ rows, const int* __restrict__ cols,
    const float* __restrict__ vals, int* __restrict__ bcur,
    i32x2* __restrict__ ebin, int E, int NB) {
  __shared__ unsigned hist[NB_MAX];
  __shared__ unsigned base[NB_MAX];
  const int tid = threadIdx.x;
  const int e0 = blockIdx.x * BIN_CHUNK;

  for (int b = tid; b < NB; b += 512) hist[b] = 0;
  __syncthreads();
  for (int k = 0; k < BIN_CHUNK / 512; ++k) {
    int e = e0 + k * 512 + tid;
    if (e < E) {
      unsigned b = (unsigned)__builtin_nontemporal_load(&rows[e]) >> SBKT_SHIFT;
      atomicAdd(&hist[b], 1u);
    }
  }
  __syncthreads();
  for (int b = tid; b < NB; b += 512) {
    unsigned c = hist[b];
    base[b] = c ? (unsigned)atomicAdd(&bcur[b], (int)c) : 0u;
    hist[b] = 0;
  }
  __syncthreads();
  for (int k = 0; k < BIN_CHUNK / 512; ++k) {
    int e = e0 + k * 512 + tid;
    if (e < E) {
      int r = rows[e];
      unsigned b = (unsigned)r >> SBKT_SHIFT;
      unsigned idx = atomicAdd(&hist[b], 1u);
      int pos = (int)(base[b] + idx);
      int c = cols[e];
      float v = vals[e];
      ebin[pos] = (i32x2){c | ((r & (SBKT_ROWS - 1)) << 20), __float_as_int(v)};
    }
  }
}

// ---- fused per-bucket sort + gather. One block per 32-row bucket:
// LDS hist -> scan -> stable scatter (sorted edges stay in LDS) -> each wave
// gathers 4 rows via readlane-broadcast + 8-deep ping-pong x-loads, writes
// support to out. Buckets > CAP processed in chunks (acc in registers).
__global__ __launch_bounds__(512) void sort_gather(
    const i32x2* __restrict__ ebin, const int* __restrict__ bbase,
    const unsigned short* __restrict__ xb, const float* __restrict__ h0,
    float* __restrict__ out, const float* __restrict__ alpha_p, int N) {
  __shared__ int cur[SBKT_ROWS];
  __shared__ int pre[SBKT_ROWS + 1];
  __shared__ i32x2 sorted[SBKT_CAP];
  const int b = blockIdx.x;
  const int r0 = b << SBKT_SHIFT;
  const int tid = threadIdx.x;
  const int wave = tid >> 6, lane = tid & 63;
  const float alpha = *alpha_p;
  int seg = bbase[b];
  const int segend = bbase[b + 1];
  const unsigned short* xbl = xb + lane * 4;

  f32x4 accA[4], accB[4];
#pragma unroll
  for (int q = 0; q < 4; ++q) {
    accA[q] = (f32x4){0.f, 0.f, 0.f, 0.f};
    accB[q] = (f32x4){0.f, 0.f, 0.f, 0.f};
  }

#define GRP_LOAD(XV, VV, JB)                                              \
  {                                                                       \
    _Pragma("unroll")                                                     \
    for (int k = 0; k < 8; ++k) {                                         \
      int col = __builtin_amdgcn_readlane(med.x, (JB) + k);               \
      VV[k] = __int_as_float(__builtin_amdgcn_readlane(med.y, (JB) + k)); \
      XV[k] = *(const u16x4*)(xbl + (size_t)col * F);                     \
    }                                                                     \
  }

#define GRP_FMA(XV, VV, AA, AB)                                           \
  {                                                                       \
    _Pragma("unroll")                                                     \
    for (int k = 0; k < 8; ++k) {                                         \
      f32x4& A = (k & 1) ? AB : AA;                                       \
      A.x += VV[k] * bf2f(XV[k][0]);                                      \
      A.y += VV[k] * bf2f(XV[k][1]);                                      \
      A.z += VV[k] * bf2f(XV[k][2]);                                      \
      A.w += VV[k] * bf2f(XV[k][3]);                                      \
    }                                                                     \
  }

  while (seg < segend) {
    int cnt = segend - seg;
    if (cnt > SBKT_CAP) cnt = SBKT_CAP;

    if (tid < SBKT_ROWS) cur[tid] = 0;
    __syncthreads();
    for (int i = tid; i < cnt; i += 512)
      atomicAdd(&cur[(ebin[seg + i].x >> 20) & (SBKT_ROWS - 1)], 1);
    __syncthreads();
    int myc = (tid < SBKT_ROWS) ? cur[tid] : 0;
    __syncthreads();
#pragma unroll
    for (int off = 1; off < SBKT_ROWS; off <<= 1) {
      int a = (tid < SBKT_ROWS && tid >= off) ? cur[tid - off] : 0;
      __syncthreads();
      if (tid < SBKT_ROWS) cur[tid] += a;
      __syncthreads();
    }
    if (tid < SBKT_ROWS) {
      int ex = cur[tid] - myc;   // exclusive prefix within chunk
      pre[tid] = ex;
      cur[tid] = ex;             // running scatter cursor
      if (tid == SBKT_ROWS - 1) pre[SBKT_ROWS] = cnt;
    }
    __syncthreads();
    for (int i = tid; i < cnt; i += 512) {
      i32x2 w = ebin[seg + i];
      int rl = (w.x >> 20) & (SBKT_ROWS - 1);
      int idx = atomicAdd(&cur[rl], 1);
      sorted[idx] = (i32x2){w.x & 0xFFFFF, w.y};
    }
    __syncthreads();

    // gather this wave's 4 rows from LDS-sorted edges
#pragma unroll
    for (int q = 0; q < 4; ++q) {
      int rho = (wave << 2) + q;
      int s = pre[rho], e2 = pre[rho + 1];
      while (s < e2) {
        int c64 = e2 - s;
        if (c64 > 64) c64 = 64;
        i32x2 med;
        if (lane < c64) med = sorted[s + lane];
        else { med.x = 0; med.y = 0; }  // col 0, val 0 -> contributes 0

        u16x4 xA[8], xB[8];
        float vA[8], vB[8];
        int jb = 0;
        GRP_LOAD(xA, vA, 0);
        while (true) {
          int jn = jb + 8;
          if (jn < c64) GRP_LOAD(xB, vB, jn);
          GRP_FMA(xA, vA, accA[q], accB[q]);
          jb = jn;
          if (jb >= c64) break;
          jn = jb + 8;
          if (jn < c64) GRP_LOAD(xA, vA, jn);
          GRP_FMA(xB, vB, accA[q], accB[q]);
          jb = jn;
          if (jb >= c64) break;  // REQUIRED: without it, c64 % 16 == 0 re-runs
                                 // FMA(A) with a stale group (double-count bug,
                                 // measured absmax 0.313 == predicted 5-sigma)
        }
        s += c64;
      }
    }
    seg += cnt;
    __syncthreads();  // protect pre/sorted before next chunk rewrites
  }
#undef GRP_LOAD
#undef GRP_FMA

  const float om = 1.0f - alpha;
#pragma unroll
  for (int q = 0; q < 4; ++q) {
    int r = r0 + (wave << 2) + q;
    if (r < N) {
      f32x4 bb = __builtin_nontemporal_load((const f32x4*)(h0 + (size_t)r * F) + lane);
      f32x4 o = om * (accA[q] + accB[q]) + alpha * bb;
      *((f32x4*)(out + (size_t)r * F) + lane) = o;
    }
  }
}

// ========================= fallback CSR path =========================
__global__ void hist_rows(const int* __restrict__ rows, int* counts, int E) {
  int e = blockIdx.x * 256 + threadIdx.x;
  if (e < E) atomicAdd(&counts[__builtin_nontemporal_load(&rows[e])], 1);
}

__global__ void scan1(const int* __restrict__ counts, int* row_start, int* blk, int N) {
  __shared__ int tmp[256];
  int t = threadIdx.x;
  int i = blockIdx.x * 256 + t;
  int v = (i < N) ? counts[i] : 0;
  tmp[t] = v;
  __syncthreads();
#pragma unroll
  for (int off = 1; off < 256; off <<= 1) {
    int a = (t >= off) ? tmp[t - off] : 0;
    __syncthreads();
    tmp[t] += a;
    __syncthreads();
  }
  if (i < N) row_start[i] = tmp[t] - v;
  if (t == 255) blk[blockIdx.x] = tmp[255];
}

__global__ void scan2(int* blk, int NB) {
  __shared__ int tmp[512];
  int t = threadIdx.x;
  int v = (t < NB) ? blk[t] : 0;
  tmp[t] = v;
  __syncthreads();
#pragma unroll
  for (int off = 1; off < 512; off <<= 1) {
    int a = (t >= off) ? tmp[t - off] : 0;
    __syncthreads();
    tmp[t] += a;
    __syncthreads();
  }
  if (t < NB) blk[t] = tmp[t] - v;
}

__global__ void scan3(const int* __restrict__ counts, int* row_start,
                      const int* __restrict__ blk, int* fill_ptr, int N) {
  int i = blockIdx.x * 256 + threadIdx.x;
  if (i >= N) return;
  int rs = row_start[i] + blk[i >> 8];
  row_start[i] = rs;
  fill_ptr[i] = rs;
  if (i == N - 1) row_start[N] = rs + counts[i];
}

__global__ void fill_csr(const int* __restrict__ rows, const int* __restrict__ cols,
                         const float* __restrict__ vals, int* fill_ptr,
                         int2* __restrict__ edges, int E) {
  int e = blockIdx.x * 256 + threadIdx.x;
  if (e >= E) return;
  int r = __builtin_nontemporal_load(&rows[e]);
  int c = __builtin_nontemporal_load(&cols[e]);
  float v = __builtin_nontemporal_load(&vals[e]);
  int pos = atomicAdd(&fill_ptr[r], 1);
  edges[pos] = make_int2(c, __float_as_int(v));
}

// fallback gather (bf16), one wave per row on global CSR
__global__ __launch_bounds__(256) void gather_rows_bf16(
    const unsigned short* __restrict__ xb, const float* __restrict__ h0,
    const int* __restrict__ row_start, const i32x2* __restrict__ edges,
    float* __restrict__ support, const float* __restrict__ alpha_p, int N) {
  int gid = blockIdx.x * 256 + threadIdx.x;
  int r = gid >> 6;
  if (r >= N) return;
  int lane = threadIdx.x & 63;
  float alpha = *alpha_p;
  int s = row_start[r], e = row_start[r + 1];
  const unsigned short* xbl = xb + lane * 4;
  f32x4 acc0 = (f32x4){0.f, 0.f, 0.f, 0.f};
  f32x4 acc1 = (f32x4){0.f, 0.f, 0.f, 0.f};

#define GRP_LOAD8(XV, VV, JB)                                             \
  {                                                                       \
    _Pragma("unroll")                                                     \
    for (int k = 0; k < 8; ++k) {                                         \
      int col = __builtin_amdgcn_readlane(med.x, (JB) + k);               \
      VV[k] = __int_as_float(__builtin_amdgcn_readlane(med.y, (JB) + k)); \
      XV[k] = *(const u16x4*)(xbl + (size_t)col * F);                     \
    }                                                                     \
  }
#define GRP_FMA8(XV, VV)                                                  \
  {                                                                       \
    _Pragma("unroll")                                                     \
    for (int k = 0; k < 8; ++k) {                                         \
      f32x4& A = (k & 1) ? acc1 : acc0;                                   \
      A.x += VV[k] * bf2f(XV[k][0]);                                      \
      A.y += VV[k] * bf2f(XV[k][1]);                                      \
      A.z += VV[k] * bf2f(XV[k][2]);                                      \
      A.w += VV[k] * bf2f(XV[k][3]);                                      \
    }                                                                     \
  }

  while (s < e) {
    int cnt = e - s;
    if (cnt > 64) cnt = 64;
    i32x2 med;
    if (lane < cnt) med = edges[s + lane];
    else { med.x = 0; med.y = 0; }
    u16x4 xA[8], xB[8];
    float vA[8], vB[8];
    int jb = 0;
    GRP_LOAD8(xA, vA, 0);
    while (true) {
      int jn = jb + 8;
      if (jn < cnt) GRP_LOAD8(xB, vB, jn);
      GRP_FMA8(xA, vA);
      jb = jn;
      if (jb >= cnt) break;
      jn = jb + 8;
      if (jn < cnt) GRP_LOAD8(xA, vA, jn);
      GRP_FMA8(xB, vB);
      jb = jn;
      if (jb >= cnt) break;  // REQUIRED: see sort_gather comment
    }
    s += cnt;
  }
#undef GRP_LOAD8
#undef GRP_FMA8

  f32x4 acc = acc0 + acc1;
  f32x4 b = __builtin_nontemporal_load((const f32x4*)(h0 + (size_t)r * F) + lane);
  float om = 1.0f - alpha;
  f32x4 o = om * acc + alpha * b;
  *((f32x4*)(support + (size_t)r * F) + lane) = o;
}

// fallback gather (fp32 x) if ws can't hold xb
__global__ __launch_bounds__(256) void gather_rows_f32(
    const float* __restrict__ x, const float* __restrict__ h0,
    const int* __restrict__ row_start, const i32x2* __restrict__ edges,
    float* __restrict__ support, const float* __restrict__ alpha_p, int N) {
  int gid = blockIdx.x * 256 + threadIdx.x;
  int r = gid >> 6;
  if (r >= N) return;
  int lane = threadIdx.x & 63;
  float alpha = *alpha_p;
  int s = row_start[r], e = row_start[r + 1];
  f32x4 acc = (f32x4){0.f, 0.f, 0.f, 0.f};
  if (s < e) {
    i32x2 ed = __builtin_nontemporal_load(&edges[s]);
    f32x4 xv = *((const f32x4*)(x + (size_t)ed.x * F) + lane);
    for (int j = s; j < e; ++j) {
      i32x2 cur = ed;
      f32x4 xc = xv;
      if (j + 1 < e) {
        ed = __builtin_nontemporal_load(&edges[j + 1]);
        xv = *((const f32x4*)(x + (size_t)ed.x * F) + lane);
      }
      float v = __int_as_float(cur.y);
      acc += v * xc;
    }
  }
  f32x4 b = __builtin_nontemporal_load((const f32x4*)(h0 + (size_t)r * F) + lane);
  float om = 1.0f - alpha;
  f32x4 o = om * acc + alpha * b;
  *((f32x4*)(support + (size_t)r * F) + lane) = o;
}

// ---- GEMM + epilogue: out = theta*(support@W) + (1-theta)*support ----
// support and out alias (in-place): tile fully staged to LDS before writes.
__global__ __launch_bounds__(256) void gemm_epilogue(
    const float* support, const unsigned short* __restrict__ Wt, float* out,
    const float* __restrict__ lamda_p, const int* __restrict__ l_p, int N) {
  __shared__ unsigned short sup[64][264];  // +8 pad: 2-way bank alias (free)

  const float theta = logf(*lamda_p / (float)(*l_p) + 1.0f);
  const float one_m_t = 1.0f - theta;

  const int m0 = blockIdx.x * 64;
  const int t = threadIdx.x;

#pragma unroll
  for (int i = 0; i < 16; ++i) {
    int f = t + i * 256;
    int row = f >> 6, c4 = f & 63;
    int g_row = m0 + row;
    f32x4 a = (f32x4){0.f, 0.f, 0.f, 0.f};
    if (g_row < N)
      a = __builtin_nontemporal_load((const f32x4*)(support + (size_t)g_row * F) + c4);
    unsigned short* p = &sup[row][c4 << 2];
    p[0] = f2bf(a.x); p[1] = f2bf(a.y); p[2] = f2bf(a.z); p[3] = f2bf(a.w);
  }
  __syncthreads();

  const int wave = t >> 6, lane = t & 63;
  const int quad = lane >> 4, lcol = lane & 15;
  const int mrow = wave * 16;

  f32x4 acc[16];
#pragma unroll
  for (int n = 0; n < 16; ++n) acc[n] = (f32x4){0.f, 0.f, 0.f, 0.f};

#pragma unroll
  for (int k = 0; k < 8; ++k) {
    short8 afrag = *(const short8*)&sup[mrow + lcol][k * 32 + quad * 8];
#pragma unroll
    for (int n = 0; n < 16; ++n) {
      short8 bfrag = *(const short8*)&Wt[(size_t)(n * 16 + lcol) * F + k * 32 + quad * 8];
      acc[n] = __builtin_amdgcn_mfma_f32_16x16x32_bf16(afrag, bfrag, acc[n], 0, 0, 0);
    }
  }

#pragma unroll
  for (int n = 0; n < 16; ++n) {
#pragma unroll
    for (int r = 0; r < 4; ++r) {
      int lrow = mrow + quad * 4 + r;
      int col = n * 16 + lcol;
      int g_row = m0 + lrow;
      if (g_row < N) {
        float s = bf2f(sup[lrow][col]);
        __builtin_nontemporal_store(theta * acc[n][r] + one_m_t * s,
                                    &out[(size_t)g_row * F + col]);
      }
    }
  }
}

extern "C" void kernel_launch(void* const* d_in, const int* in_sizes, int n_in,
                              void* d_out, int out_size, void* d_ws, size_t ws_size,
                              hipStream_t stream) {
  const float* x     = (const float*)d_in[0];
  const int*   rows  = (const int*)d_in[1];
  const int*   cols  = (const int*)d_in[2];
  const float* vals  = (const float*)d_in[3];
  const float* h0    = (const float*)d_in[4];
  const float* W     = (const float*)d_in[5];
  const float* lamda = (const float*)d_in[6];
  const float* alpha = (const float*)d_in[7];
  const int*   lp    = (const int*)d_in[8];

  const int E = in_sizes[1];
  const int N = in_sizes[0] / F;
  const int NF = N * F;
  const int NB = (N + SBKT_ROWS - 1) >> SBKT_SHIFT;

  // ---- workspace layout (256B aligned regions) ----
  size_t off = 0;
  auto take = [&](size_t bytes) { size_t o = off; off += (bytes + 255) & ~(size_t)255; return o; };
  char* ws = (char*)d_ws;
  unsigned short* Wt  = (unsigned short*)(ws + take((size_t)F * F * 2));
  int* counts    = (int*)(ws + take((size_t)N * 4));         // fallback only
  int* row_start = (int*)(ws + take((size_t)(N + 1) * 4));   // fallback only
  int* fill_ptr  = (int*)(ws + take((size_t)N * 4));         // fallback only
  int* blk       = (int*)(ws + take(4096));                  // fallback only
  int* bucket_counts = (int*)(ws + take((size_t)NB_MAX * 4));
  int* bbase     = (int*)(ws + take((size_t)(NB_MAX + 1) * 4));
  int* bcur      = (int*)(ws + take((size_t)NB_MAX * 4));
  i32x2* edges   = (i32x2*)(ws + take((size_t)E * 8));
  unsigned short* xb = (unsigned short*)(ws + take((size_t)NF * 2));
  const int use_bf16 = (off <= ws_size);

  float* out = (float*)d_out;

  // fused bucket path: needs bf16 x, 20-bit cols, NB within LDS hist bounds
  const int use_sort = use_bf16 && (E > 0) && (N <= (1 << 20)) && (NB <= NB_MAX);

  int nxb = use_bf16 ? (NF + 2047) / 2048 : 0;
  int eb = (E + 255) / 256;
  int nb = (N + 255) / 256;  // must be <= 512 for scan2 (N=100000 -> 391)
  int bchunks = (E + BIN_CHUNK - 1) / BIN_CHUNK;

  if (use_sort) {
    hipMemsetAsync(bucket_counts, 0, (size_t)NB * sizeof(int), stream);
    prep<<<256 + nxb + bchunks, 256, 0, stream>>>(W, Wt, x, xb, NF, rows,
                                                  bucket_counts, nxb, E, NB);
    scan_buckets<<<1, 1024, 0, stream>>>(bucket_counts, bbase, bcur, NB, E);
    bin_edges<<<bchunks, 512, 0, stream>>>(rows, cols, vals, bcur, edges, E, NB);
    sort_gather<<<NB, 512, 0, stream>>>(edges, bbase, xb, h0, out, alpha, N);
  } else {
    prep<<<256 + nxb, 256, 0, stream>>>(W, Wt, x, xb, NF, rows,
                                        bucket_counts, nxb, E, 0);
    hipMemsetAsync(counts, 0, (size_t)N * sizeof(int), stream);
    hist_rows<<<eb, 256, 0, stream>>>(rows, counts, E);
    scan1<<<nb, 256, 0, stream>>>(counts, row_start, blk, N);
    scan2<<<1, 512, 0, stream>>>(blk, nb);
    scan3<<<nb, 256, 0, stream>>>(counts, row_start, blk, fill_ptr, N);
    fill_csr<<<eb, 256, 0, stream>>>(rows, cols, vals, fill_ptr, (int2*)edges, E);
    int gather_blocks = (N * 64 + 255) / 256;
    if (use_bf16) {
      gather_rows_bf16<<<gather_blocks, 256, 0, stream>>>(xb, h0, row_start, edges,
                                                          out, alpha, N);
    } else {
      gather_rows_f32<<<gather_blocks, 256, 0, stream>>>(x, h0, row_start, edges,
                                                         out, alpha, N);
    }
  }

  gemm_epilogue<<<(N + 63) / 64, 256, 0, stream>>>(out, Wt, out, lamda, lp, N);
}